// Round 1
// 185.019 us; speedup vs baseline: 1.0184x; 1.0184x over previous
//
#include <hip/hip_runtime.h>

// YOLOv1-style loss: S=7, B=2, C=20, L=49, n=16384.
// preds row: [ pcls: 980 | pconf: 98 | pbox: 392 ] = 1470 floats
// labels row: L * [ obj(1) | tcls(20) | tbox(4) ] = 1225 floats
// Weights: NOOBJ=0.5, OBJ=0.5, CLS=0.5, COORD=2.5
//
// R8: drop conf+pbox LDS staging. Evidence: top-5 dispatches are all
// 56us harness re-poison fills (385MB @ 6.8TB/s); loss kernel <56us,
// plateaued ~50us vs ~20us BW floor on ~127MB cold traffic. Theory:
// LDS-capped occupancy (27.8KB -> 5 blk/CU = 20 waves) is thin for two
// serialized cold-load phases, and 85% of staged pbox bytes are dead
// (obj rate 15%). Fix: conf = coalesced direct float2 (lane l reads
// exactly conf[2l..2l+1], contiguous across wave -- LDS buys nothing);
// pbox = 4 gated float2 direct loads, obj lanes only. Labels staging
// (the only真 coalescing win) unchanged. LDS 19.4KB -> 8 blk/CU by LDS;
// launch_bounds(256,6) targets 24+ waves/CU. Traffic ~127->~114MB.

#define L_CELLS 49
#define PRED_ROW 1470
#define LAB_ROW 1225
#define CONF_BASE 980
#define BOX_BASE 1078
#define W_NOOBJ 0.5f
#define W_OBJ 0.5f
#define W_CLS 0.5f
#define W_COORD 2.5f
#define INV_S (1.0f / 7.0f)

#define LAB_SLOTS 308  // ceil((3 + 1225)/4)
#define WAVE_SLOTS 310 // +pad

__global__ __launch_bounds__(256, 6) void yolo_loss_kernel(
    const float* __restrict__ preds, const float* __restrict__ labels,
    float* __restrict__ ws) {
  __shared__ float4 st[4][WAVE_SLOTS];  // 19840 B/block

  const int tid = threadIdx.x;
  const int w = tid >> 6;
  const int lane = tid & 63;
  const int s = blockIdx.x * 4 + w;
  float4* stw = st[w];

  // ---- stage labels row only (align-down; <=16B page-safe overread on
  // final row -- same pattern verified in R5-R7) ----
  size_t g0 = (size_t)s * LAB_ROW;
  size_t ga = g0 & ~(size_t)3;
  int loff = (int)(g0 - ga);
#pragma unroll
  for (int r = 0; r < 5; ++r) {
    int i = lane + 64 * r;
    if (i < LAB_SLOTS) stw[i] = *(const float4*)(labels + ga + 4 * (size_t)i);
  }

  const float* lab = (const float*)stw + loff;  // lab[25l + k]
  const float* rp = preds + (size_t)s * PRED_ROW;

  float acc = 0.0f;
  if (lane < L_CELLS) {
    const int l = lane;
    // conf: coalesced direct load, 8B/lane, 8B-aligned (byte 5880s+3920+8l)
    float2 cf = *(const float2*)(rp + CONF_BASE + 2 * l);
    float c0v = cf.x, c1v = cf.y;
    float objf = lab[25 * l];

    if (objf != 0.0f) {
      // pbox: gated direct, 4x float2 (byte 5880s+4312+32l, 8B-aligned)
      float bx[8];
#pragma unroll
      for (int k = 0; k < 4; ++k) {
        float2 b2 = *(const float2*)(rp + BOX_BASE + 8 * l + 2 * k);
        bx[2 * k] = b2.x;
        bx[2 * k + 1] = b2.y;
      }
      float tx = lab[25 * l + 21], ty = lab[25 * l + 22];
      float tw = lab[25 * l + 23], th = lab[25 * l + 24];
      float t0 = tx * INV_S, t1 = ty * INV_S, t2 = tw, t3 = th;

      float iou[2], rmse2[2];
#pragma unroll
      for (int b = 0; b < 2; ++b) {
        float o0 = bx[4 * b + 0] * INV_S;
        float o1 = bx[4 * b + 1] * INV_S;
        float o2 = bx[4 * b + 2] * bx[4 * b + 2];
        float o3 = bx[4 * b + 3] * bx[4 * b + 3];
        float left = fmaxf(t0 - 0.5f * t2, o0 - 0.5f * o2);
        float right = fminf(t0 + 0.5f * t2, o0 + 0.5f * o2);
        float top = fmaxf(t1 - 0.5f * t3, o1 - 0.5f * o3);
        float bot = fminf(t1 + 0.5f * t3, o1 + 0.5f * o3);
        float wd = right - left;
        float h = bot - top;
        bool invalid = (wd < 0.0f) || (h < 0.0f);
        float inter = invalid ? 0.0f : wd * h;
        float uni = t2 * t3 + o2 * o3 - inter;
        iou[b] = invalid ? 0.0f : inter / fmaxf(uni, 1e-12f);
        float d0 = t0 - o0, d1 = t1 - o1, d2 = t2 - o2, d3 = t3 - o3;
        rmse2[b] = d0 * d0 + d1 * d1 + d2 * d2 + d3 * d3;  // sqrt monotone
      }

      float max_iou = fmaxf(iou[0], iou[1]);
      // jnp.argmax/argmin: first index wins ties -> strict compare for idx 1
      int best;
      if (max_iou > 0.0f)
        best = (iou[1] > iou[0]) ? 1 : 0;
      else
        best = (rmse2[1] < rmse2[0]) ? 1 : 0;
      float best_iou = iou[best];

      float cb = (best == 0) ? c0v : c1v;
      float co = (best == 0) ? c1v : c0v;
      float db = best_iou - cb;
      acc += W_OBJ * db * db + W_NOOBJ * co * co;

      // cls: pcls direct from global (10x float2, 8B-aligned, ~15% lanes),
      // tcls from staged labels
      float clsacc = 0.0f;
#pragma unroll
      for (int k = 0; k < 10; ++k) {
        float2 p = *(const float2*)(rp + 20 * l + 2 * k);
        float d0 = lab[25 * l + 1 + 2 * k] - p.x;
        float d1 = lab[25 * l + 2 + 2 * k] - p.y;
        clsacc += d0 * d0 + d1 * d1;
      }
      acc += W_CLS * clsacc;

      // coord: (tx, ty, sqrt(tw), sqrt(th)) vs best raw box
      float e0 = tx - bx[best * 4 + 0];
      float e1 = ty - bx[best * 4 + 1];
      float e2 = sqrtf(tw) - bx[best * 4 + 2];
      float e3 = sqrtf(th) - bx[best * 4 + 3];
      acc += W_COORD * (e0 * e0 + e1 * e1 + e2 * e2 + e3 * e3);
    } else {
      acc += W_NOOBJ * (c0v * c0v + c1v * c1v);
    }
  }

  // ---- reduce: wave(64) shuffle -> LDS -> one ws slot per block ----
#pragma unroll
  for (int o = 32; o > 0; o >>= 1) acc += __shfl_down(acc, o);

  __shared__ float wsum[4];
  if (lane == 0) wsum[w] = acc;
  __syncthreads();
  if (tid == 0) ws[blockIdx.x] = wsum[0] + wsum[1] + wsum[2] + wsum[3];
}

__global__ __launch_bounds__(1024) void final_reduce_kernel(
    const float* __restrict__ ws, float* __restrict__ out, int m) {
  float acc = 0.0f;
  for (int i = threadIdx.x; i < m; i += 1024) acc += ws[i];
#pragma unroll
  for (int o = 32; o > 0; o >>= 1) acc += __shfl_down(acc, o);
  __shared__ float wsum[16];
  int wave = threadIdx.x >> 6;
  int lane = threadIdx.x & 63;
  if (lane == 0) wsum[wave] = acc;
  __syncthreads();
  if (threadIdx.x == 0) {
    float sum = 0.0f;
#pragma unroll
    for (int i = 0; i < 16; ++i) sum += wsum[i];
    out[0] = sum;
  }
}

extern "C" void kernel_launch(void* const* d_in, const int* in_sizes, int n_in,
                              void* d_out, int out_size, void* d_ws, size_t ws_size,
                              hipStream_t stream) {
  const float* preds = (const float*)d_in[0];
  const float* labels = (const float*)d_in[1];
  float* out = (float*)d_out;
  float* ws = (float*)d_ws;
  int n = in_sizes[0] / PRED_ROW;  // 16384
  int blocks = n / 4;              // 4096 (wave per sample)

  yolo_loss_kernel<<<blocks, 256, 0, stream>>>(preds, labels, ws);
  final_reduce_kernel<<<1, 1024, 0, stream>>>(ws, out, blocks);
}